// Round 2
// baseline (271.313 us; speedup 1.0000x reference)
//
#include <hip/hip_runtime.h>
#include <hip/hip_bf16.h>
#include <hip/hip_fp16.h>
#include <hip/hip_cooperative_groups.h>
#include <math.h>

namespace cg = cooperative_groups;

#define N_SEQ 512
#define DIM   1024
#define HEADS 16
#define DH    64
#define P     32
#define P2    16
#define PSTR  520   // prob LDS row stride in halfs (16B-aligned rows)

typedef short    bf16x8 __attribute__((ext_vector_type(8)));
typedef _Float16 f16x8  __attribute__((ext_vector_type(8)));
typedef float    f32x4  __attribute__((ext_vector_type(4)));

__device__ inline unsigned short f2bf(float f) {
  union { float f; unsigned u; } v; v.f = f;
  unsigned r = (v.u + 0x7fffu + ((v.u >> 16) & 1u)) >> 16;
  return (unsigned short)r;
}

union H8 { f16x8 v; __half2 h2[4]; unsigned u32[4]; };

// LDS reused across phases: fold scratch (54.6 KB) / attention probs (33.4 KB)
union LdsU {
  struct { float W1s[32][33]; float Wqs[32][65]; float wsm[32][65]; float qs[64][132]; } p0;
  struct { unsigned short probS[32][PSTR]; float invS[32]; } p2;
};

// score of one i-row vs 16 j's: packed relu(a+c) via ext-vector ops
// (lowers to v_pk_add_f16 + v_pk_max_f16), b2 folded into acc init.
__device__ inline float rowscore(const H8& a, const H8& c, f16x8 w2f,
                                 f32x4 b2q, float4 w3q) {
  const f16x8 z = (f16x8)(_Float16)0;
  const f16x8 u = __builtin_elementwise_max(a.v + c.v, z);
  f32x4 acc = b2q;                     // MFMA C-in carries +b2 for free
  acc = __builtin_amdgcn_mfma_f32_16x16x32_f16(w2f, u, acc, 0, 0, 0);
  return fmaxf(acc[0], 0.f) * w3q.x + fmaxf(acc[1], 0.f) * w3q.y
       + fmaxf(acc[2], 0.f) * w3q.z + fmaxf(acc[3], 0.f) * w3q.w;
}

__device__ inline float quadreduce4(float p0, float p1, float p2, float p3,
                                    int quad) {
  // 3-shfl 4x4 transpose-reduce: quad q returns sum over quads of p_q.
  const float sx = (quad & 1) ? p0 : p1;
  const float sy = (quad & 1) ? p2 : p3;
  const float rx = __shfl_xor(sx, 16);
  const float ry = __shfl_xor(sy, 16);
  const float aa = ((quad & 1) ? p1 : p0) + rx;
  const float bb = ((quad & 1) ? p3 : p2) + ry;
  const float sz = (quad & 2) ? aa : bb;
  const float rz = __shfl_xor(sz, 32);
  return ((quad & 2) ? bb : aa) + rz;
}

// ---------------------------------------------------------------------------
// One cooperative kernel, 256 blocks x 256 threads, 4 phases / 3 grid syncs:
//   0: bf16 casts (x, Wout, v-rows) + weight folding -> Wcomb, ba32, bc32(+b1)
//   1: Y(512x2048) = xb @ Wcomb^T -> fp16 a / cb / vT
//   2: fused scores + softmax + PV (mirror-balanced causal pairs)
//   3: out(512x1024) = attnb @ Woutb^T
// ---------------------------------------------------------------------------
__global__ __launch_bounds__(256) void fused_all(
    const float* __restrict__ x, const float* __restrict__ Wqkv,
    const float* __restrict__ Wout, const float* __restrict__ Wq,
    const float* __restrict__ bq, const float* __restrict__ Wk,
    const float* __restrict__ bk, const float* __restrict__ W1,
    const float* __restrict__ b1, const float* __restrict__ W2,
    const float* __restrict__ b2, const float* __restrict__ W3,
    float* __restrict__ out,
    float* __restrict__ ba32, float* __restrict__ bc32,
    __half* __restrict__ a_buf, __half* __restrict__ cb_buf,
    __half* __restrict__ vT, short* __restrict__ Wcomb,
    short* __restrict__ xb, short* __restrict__ Woutb,
    short* __restrict__ attnb) {
  const int b = blockIdx.x, tid = threadIdx.x;
  __shared__ __align__(16) LdsU sh;
  cg::grid_group grid = cg::this_grid();

  // ================= phase 0: casts + weight folding =================
  {
    // x -> bf16 (512 float4 per block)
#pragma unroll
    for (int u = 0; u < 2; ++u) {
      const int t = b * 512 + u * 256 + tid;
      const float4 v = ((const float4*)x)[t];
      ushort4 o;
      o.x = f2bf(v.x); o.y = f2bf(v.y); o.z = f2bf(v.z); o.w = f2bf(v.w);
      ((ushort4*)xb)[t] = o;
    }
    // Wout -> bf16 (1024 float4 per block)
#pragma unroll
    for (int u = 0; u < 4; ++u) {
      const int t = b * 1024 + u * 256 + tid;
      const float4 v = ((const float4*)Wout)[t];
      ushort4 o;
      o.x = f2bf(v.x); o.y = f2bf(v.y); o.z = f2bf(v.z); o.w = f2bf(v.w);
      ((ushort4*)Woutb)[t] = o;
    }
    // v-rows of Wcomb (4 rows per block)
#pragma unroll
    for (int rr = 0; rr < 4; ++rr) {
      const int ov = b * 4 + rr;
      const int hv = ov >> 6, dv = ov & 63;
      const float4 v = *(const float4*)(Wqkv + (size_t)(dv * 48 + 32 + hv) * DIM + tid * 4);
      ushort4 o;
      o.x = f2bf(v.x); o.y = f2bf(v.y); o.z = f2bf(v.z); o.w = f2bf(v.w);
      *(ushort4*)(Wcomb + (size_t)(1024 + ov) * DIM + tid * 4) = o;
    }
    // fold: Wcomb rows 0..1023 (= W1{q,k} @ W{q,k} @ Wqkv_{q,k,head})
    float (*W1s)[33]  = sh.p0.W1s;
    float (*Wqs)[65]  = sh.p0.Wqs;
    float (*wsm)[65]  = sh.p0.wsm;
    float (*qs)[132]  = sh.p0.qs;
    const int part = b >> 7, rem = b & 127;
    const int h = rem >> 3, c0 = (rem & 7) * 128;
    const int grow = part * 16 + h;
    for (int idx = tid; idx < 1024; idx += 256)
      W1s[idx >> 5][idx & 31] = W1[(idx >> 5) * 64 + part * 32 + (idx & 31)];
    const float* Wsel = part ? Wk : Wq;
    for (int idx = tid; idx < 2048; idx += 256)
      Wqs[idx >> 6][idx & 63] = Wsel[idx];
    for (int idx = tid; idx < 2048; idx += 256) {
      const int d = idx >> 5, c4 = idx & 31;
      *(float4*)&qs[d][c4 * 4] =
          *(const float4*)(Wqkv + (size_t)(d * 48 + grow) * DIM + c0 + c4 * 4);
    }
    __syncthreads();
    for (int idx = tid; idx < 2048; idx += 256) {
      const int q = idx >> 6, d = idx & 63;
      float s = 0.f;
#pragma unroll
      for (int pp = 0; pp < 32; ++pp) s += W1s[q][pp] * Wqs[pp][d];
      wsm[q][d] = s;
    }
    __syncthreads();
    for (int idx = tid; idx < 4096; idx += 256) {
      const int q = idx >> 7, c = idx & 127;
      float s = 0.f;
#pragma unroll
      for (int d = 0; d < 64; ++d) s += wsm[q][d] * qs[d][c];
      Wcomb[(size_t)(part * 512 + h * 32 + q) * DIM + c0 + c] = (short)f2bf(s);
    }
    if (rem == 0 && tid < 32) {
      const float* bsel = part ? bk : bq;
      float s = 0.f;
#pragma unroll
      for (int pp = 0; pp < 32; ++pp) s += W1s[tid][pp] * bsel[pp];
      if (part) s += b1[tid];          // fold b1 into bc32
      (part ? bc32 : ba32)[tid] = s;
    }
  }
  grid.sync();

  // ================= phase 1: main GEMM -> a / cb / vT =================
  {
    const int lane = tid & 63;
    const int m = lane & 15;
    const int quad = lane >> 4;
#pragma unroll
    for (int u = 0; u < 2; ++u) {
      const int wave = b * 4 + (tid >> 6) + u * 1024;
      const int tm = wave >> 6;
      const int tn = wave & 63;
      const short* pa  = xb + (size_t)(tm * 16 + m) * DIM + quad * 8;
      const short* pb0 = Wcomb + (size_t)(tn * 32 + m) * DIM + quad * 8;
      const short* pb1 = pb0 + (size_t)16 * DIM;
      f32x4 acc0 = {0.f,0.f,0.f,0.f}, acc1 = {0.f,0.f,0.f,0.f};
#pragma unroll 4
      for (int k = 0; k < DIM; k += 32) {
        const bf16x8 av  = *(const bf16x8*)(pa + k);
        const bf16x8 b0  = *(const bf16x8*)(pb0 + k);
        const bf16x8 b1v = *(const bf16x8*)(pb1 + k);
        acc0 = __builtin_amdgcn_mfma_f32_16x16x32_bf16(av, b0, acc0, 0, 0, 0);
        acc1 = __builtin_amdgcn_mfma_f32_16x16x32_bf16(av, b1v, acc1, 0, 0, 0);
      }
#pragma unroll
      for (int r = 0; r < 4; ++r) {
        const int n = tm * 16 + quad * 4 + r;
#pragma unroll
        for (int half = 0; half < 2; ++half) {
          const int o = tn * 32 + m + half * 16;
          const float val = half ? acc1[r] : acc0[r];
          if (o < 512) {
            const int hh = o >> 5, q = o & 31;
            a_buf[((size_t)hh * N_SEQ + n) * P + q] = __float2half(val + ba32[q]);
          } else if (o < 1024) {
            const int oo = o - 512, hh = oo >> 5, q = oo & 31;
            cb_buf[((size_t)hh * N_SEQ + n) * P + q] = __float2half(val + bc32[q]);
          } else {
            const int ov = o - 1024, hh = ov >> 6, d = ov & 63;
            vT[((size_t)hh * DH + d) * N_SEQ + n] = __float2half(val);
          }
        }
      }
    }
  }
  grid.sync();

  // ================= phase 2: fused attention =================
  {
    const int p = b & 15;                // pair index
    const int h = b >> 4;                // head
    const int w = tid >> 6;
    const int lane = tid & 63;
    const int m = lane & 15, quad = lane >> 4;
    __half (*probS)[PSTR] = reinterpret_cast<__half(*)[PSTR]>(sh.p2.probS);
    float* invS = sh.p2.invS;

    const int tlo = p, thi = 31 - p;
    const int nlo = p + 1, nhi = 32 - p;

    // ---- scores -> probS (f16, raw) ----
    {
      f16x8 w2f;
      {
        const float4* wp = (const float4*)(W2 + m * P + quad * 8);
        const float4 w0 = wp[0], w1 = wp[1];
        H8 uu;
        uu.h2[0] = __floats2half2_rn(w0.x, w0.y);
        uu.h2[1] = __floats2half2_rn(w0.z, w0.w);
        uu.h2[2] = __floats2half2_rn(w1.x, w1.y);
        uu.h2[3] = __floats2half2_rn(w1.z, w1.w);
        w2f = uu.v;
      }
      const float4 b2f = *(const float4*)(b2 + quad * 4);
      const f32x4 b2q = {b2f.x, b2f.y, b2f.z, b2f.w};
      const float4 w3q = *(const float4*)(W3 + quad * 4);

      H8 alo[4], ahi[4];
#pragma unroll
      for (int r = 0; r < 4; ++r) {
        alo[r].v = *(const f16x8*)(a_buf + ((size_t)h * N_SEQ + tlo * 16 + 4 * w + r) * P + quad * 8);
        ahi[r].v = *(const f16x8*)(a_buf + ((size_t)h * N_SEQ + thi * 16 + 4 * w + r) * P + quad * 8);
      }

      for (int jt = 0; jt < nhi; ++jt) {
        H8 cb;
        cb.v = *(const f16x8*)(cb_buf + ((size_t)h * N_SEQ + jt * 16 + m) * P + quad * 8);
        const float q0 = rowscore(ahi[0], cb, w2f, b2q, w3q);
        const float q1 = rowscore(ahi[1], cb, w2f, b2q, w3q);
        const float q2 = rowscore(ahi[2], cb, w2f, b2q, w3q);
        const float q3 = rowscore(ahi[3], cb, w2f, b2q, w3q);
        const float fh = quadreduce4(q0, q1, q2, q3, quad);
        probS[16 + 4 * w + quad][jt * 16 + m] = __float2half(fh);
        if (jt < nlo) {
          const float s0 = rowscore(alo[0], cb, w2f, b2q, w3q);
          const float s1 = rowscore(alo[1], cb, w2f, b2q, w3q);
          const float s2 = rowscore(alo[2], cb, w2f, b2q, w3q);
          const float s3 = rowscore(alo[3], cb, w2f, b2q, w3q);
          const float fl = quadreduce4(s0, s1, s2, s3, quad);
          probS[4 * w + quad][jt * 16 + m] = __float2half(fl);
        }
      }
    }
    __syncthreads();

    // ---- per-row softmax; store UNNORMALIZED exp, inv in invS ----
    {
      const int lr = 8 * w + (lane >> 3);
      const int c  = lane & 7;
      const int gi = (lr < 16) ? (tlo * 16 + lr) : (thi * 16 + (lr - 16));
      float mx = -1e30f;
#pragma unroll
      for (int k = 0; k < 8; ++k) {
        const int c0 = k * 64 + c * 8;
        if (c0 > gi) break;
        H8 vv; vv.v = *(const f16x8*)&probS[lr][c0];
#pragma unroll
        for (int uu = 0; uu < 8; ++uu) {
          const float s = __half2float(vv.h2[uu >> 1].data[uu & 1]);
          if (c0 + uu <= gi) mx = fmaxf(mx, s);
        }
      }
#pragma unroll
      for (int msk = 1; msk < 8; msk <<= 1) mx = fmaxf(mx, __shfl_xor(mx, msk));
      float sum = 0.f;
#pragma unroll
      for (int k = 0; k < 8; ++k) {
        const int c0 = k * 64 + c * 8;
        H8 vv; vv.v = *(const f16x8*)&probS[lr][c0];
        H8 o;
#pragma unroll
        for (int uu = 0; uu < 4; ++uu) {
          float e0 = 0.f, e1 = 0.f;
          if (c0 + 2 * uu <= gi) {
            e0 = __expf(__half2float(vv.h2[uu].data[0]) - mx);
            if (c0 + 2 * uu + 1 <= gi)
              e1 = __expf(__half2float(vv.h2[uu].data[1]) - mx);
          }
          sum += e0 + e1;
          o.h2[uu] = __floats2half2_rn(e0, e1);
        }
        *(f16x8*)&probS[lr][c0] = o.v;
      }
#pragma unroll
      for (int msk = 1; msk < 8; msk <<= 1) sum += __shfl_xor(sum, msk);
      if (c == 0) invS[lr] = 1.f / sum;
    }
    __syncthreads();

    // ---- PV: wave w -> d-tile w for both i-tiles ----
    {
      const int d0 = w * 16;
      const __half* pb = vT + ((size_t)h * DH + d0 + m) * N_SEQ + quad * 8;
#pragma unroll
      for (int half = 0; half < 2; ++half) {
        const int lbase = half ? 16 : 0;
        const int tile = half ? thi : tlo;
        const int nk = half ? ((33 - p) >> 1) : ((p + 2) >> 1);
        f32x4 acc = {0.f, 0.f, 0.f, 0.f};
        for (int k = 0; k < nk; ++k) {
          const f16x8 aa = *(const f16x8*)&probS[lbase + m][k * 32 + quad * 8];
          const f16x8 bb = *(const f16x8*)(pb + k * 32);
          acc = __builtin_amdgcn_mfma_f32_16x16x32_f16(aa, bb, acc, 0, 0, 0);
        }
#pragma unroll
        for (int r = 0; r < 4; ++r) {
          const int lrow = quad * 4 + r;
          const float val = acc[r] * invS[lbase + lrow];
          attnb[(size_t)(tile * 16 + lrow) * DIM + h * DH + d0 + m] = (short)f2bf(val);
        }
      }
    }
  }
  grid.sync();

  // ================= phase 3: output GEMM =================
  {
    const int lane = tid & 63;
    const int m = lane & 15, quad = lane >> 4;
#pragma unroll
    for (int u = 0; u < 2; ++u) {
      const int wave = b * 4 + (tid >> 6) + u * 1024;
      const int tm = wave >> 6;
      const int tn = wave & 63;
      const short* pa = attnb + (size_t)(tm * 16 + m) * DIM + quad * 8;
      const short* pb = Woutb + (size_t)(tn * 16 + m) * DIM + quad * 8;
      f32x4 acc = {0.f, 0.f, 0.f, 0.f};
#pragma unroll 4
      for (int k = 0; k < DIM; k += 32) {
        const bf16x8 aa = *(const bf16x8*)(pa + k);
        const bf16x8 bb = *(const bf16x8*)(pb + k);
        acc = __builtin_amdgcn_mfma_f32_16x16x32_bf16(aa, bb, acc, 0, 0, 0);
      }
#pragma unroll
      for (int r = 0; r < 4; ++r)
        out[(size_t)(tm * 16 + quad * 4 + r) * DIM + tn * 16 + m] = acc[r];
    }
  }
}

// ---------------------------------------------------------------------------
extern "C" void kernel_launch(void* const* d_in, const int* in_sizes, int n_in,
                              void* d_out, int out_size, void* d_ws, size_t ws_size,
                              hipStream_t stream) {
  const float* x    = (const float*)d_in[0];
  const float* Wqkv = (const float*)d_in[1];
  const float* Wout = (const float*)d_in[2];
  const float* Wq   = (const float*)d_in[3];
  const float* bq   = (const float*)d_in[4];
  const float* Wk   = (const float*)d_in[5];
  const float* bk   = (const float*)d_in[6];
  const float* W1   = (const float*)d_in[7];
  const float* b1   = (const float*)d_in[8];
  const float* W2   = (const float*)d_in[9];
  const float* b2   = (const float*)d_in[10];
  const float* W3   = (const float*)d_in[11];
  float* out = (float*)d_out;

  float*  ws     = (float*)d_ws;
  float*  ba32   = ws;                                   // 32
  float*  bc32   = ba32 + 32;                            // 32 (b1 pre-folded)
  __half* a_buf  = (__half*)(bc32 + 32);                 // 16*512*32
  __half* cb_buf = a_buf + (size_t)HEADS * N_SEQ * P;    // 16*512*32
  __half* vT     = cb_buf + (size_t)HEADS * N_SEQ * P;   // 16*64*512
  short*  Wcomb  = (short*)(vT + (size_t)HEADS * DH * N_SEQ); // 2048*1024
  short*  xb     = Wcomb + (size_t)2048 * DIM;           // 512*1024
  short*  Woutb  = xb + (size_t)N_SEQ * DIM;             // 1024*1024
  short*  attnb  = Woutb + (size_t)DIM * DIM;            // 512*1024

  void* args[] = {
      (void*)&x, (void*)&Wqkv, (void*)&Wout, (void*)&Wq, (void*)&bq,
      (void*)&Wk, (void*)&bk, (void*)&W1, (void*)&b1, (void*)&W2,
      (void*)&b2, (void*)&W3, (void*)&out, (void*)&ba32, (void*)&bc32,
      (void*)&a_buf, (void*)&cb_buf, (void*)&vT, (void*)&Wcomb,
      (void*)&xb, (void*)&Woutb, (void*)&attnb};

  (void)hipLaunchCooperativeKernel(fused_all, dim3(256), dim3(256), args, 0,
                                   stream);
}

// Round 3
// 199.519 us; speedup vs baseline: 1.3598x; 1.3598x over previous
//
#include <hip/hip_runtime.h>
#include <hip/hip_bf16.h>
#include <hip/hip_fp16.h>
#include <math.h>

#define N_SEQ 512
#define DIM   1024
#define HEADS 16
#define DH    64
#define P     32
#define P2    16
#define PSTR  520   // prob LDS row stride in halfs (16B-aligned rows)

typedef short    bf16x8 __attribute__((ext_vector_type(8)));
typedef _Float16 f16x8  __attribute__((ext_vector_type(8)));
typedef float    f32x4  __attribute__((ext_vector_type(4)));

__device__ inline unsigned short f2bf(float f) {
  union { float f; unsigned u; } v; v.f = f;
  unsigned r = (v.u + 0x7fffu + ((v.u >> 16) & 1u)) >> 16;
  return (unsigned short)r;
}

union H8 { f16x8 v; __half2 h2[4]; unsigned u32[4]; };

// ---------------------------------------------------------------------------
// Fused prep: weight folding + all bf16 casts. 768 blocks.
// ---------------------------------------------------------------------------
__global__ __launch_bounds__(256) void prep(
    const float* __restrict__ Wqkv, const float* __restrict__ Wq,
    const float* __restrict__ bq, const float* __restrict__ Wk,
    const float* __restrict__ bk, const float* __restrict__ W1,
    const float* __restrict__ b1,
    const float* __restrict__ x, const float* __restrict__ Wout,
    short* __restrict__ Wcomb, short* __restrict__ xb,
    short* __restrict__ Woutb, float* __restrict__ ba32,
    float* __restrict__ bc32) {
  const int b = blockIdx.x, tid = threadIdx.x;
  if (b < 256) {
    __shared__ float W1s[32][33];
    __shared__ float Wqs[32][65];
    __shared__ float wsm[32][65];
    __shared__ __align__(16) float qs[64][132];
    const int part = b >> 7, rem = b & 127;
    const int h = rem >> 3, c0 = (rem & 7) * 128;
    const int grow = part * 16 + h;
    for (int idx = tid; idx < 1024; idx += 256)
      W1s[idx >> 5][idx & 31] = W1[(idx >> 5) * 64 + part * 32 + (idx & 31)];
    const float* Wsel = part ? Wk : Wq;
    for (int idx = tid; idx < 2048; idx += 256)
      Wqs[idx >> 6][idx & 63] = Wsel[idx];
    for (int idx = tid; idx < 2048; idx += 256) {
      const int d = idx >> 5, c4 = idx & 31;
      *(float4*)&qs[d][c4 * 4] =
          *(const float4*)(Wqkv + (size_t)(d * 48 + grow) * DIM + c0 + c4 * 4);
    }
    __syncthreads();
    for (int idx = tid; idx < 2048; idx += 256) {
      const int q = idx >> 6, d = idx & 63;
      float s = 0.f;
#pragma unroll
      for (int p = 0; p < 32; ++p) s += W1s[q][p] * Wqs[p][d];
      wsm[q][d] = s;
    }
    __syncthreads();
    for (int idx = tid; idx < 4096; idx += 256) {
      const int q = idx >> 7, c = idx & 127;
      float s = 0.f;
#pragma unroll
      for (int d = 0; d < 64; ++d) s += wsm[q][d] * qs[d][c];
      Wcomb[(size_t)(part * 512 + h * 32 + q) * DIM + c0 + c] = (short)f2bf(s);
    }
    if (rem == 0 && tid < 32) {
      const float* bsel = part ? bk : bq;
      float s = 0.f;
#pragma unroll
      for (int p = 0; p < 32; ++p) s += W1s[tid][p] * bsel[p];
      if (part) s += b1[tid];          // fold b1 into bc32
      (part ? bc32 : ba32)[tid] = s;
    }
  } else if (b < 384) {
#pragma unroll
    for (int rr = 0; rr < 8; ++rr) {
      const int ov = (b - 256) * 8 + rr;
      const int h = ov >> 6, d = ov & 63;
      const float4 v = *(const float4*)(Wqkv + (size_t)(d * 48 + 32 + h) * DIM + tid * 4);
      ushort4 o;
      o.x = f2bf(v.x); o.y = f2bf(v.y); o.z = f2bf(v.z); o.w = f2bf(v.w);
      *(ushort4*)(Wcomb + (size_t)(1024 + ov) * DIM + tid * 4) = o;
    }
  } else if (b < 512) {
    const int idx = (b - 384) * 256 + tid;
#pragma unroll
    for (int u = 0; u < 4; ++u) {
      const int t = u * 32768 + idx;
      const float4 v = ((const float4*)x)[t];
      ushort4 o;
      o.x = f2bf(v.x); o.y = f2bf(v.y); o.z = f2bf(v.z); o.w = f2bf(v.w);
      ((ushort4*)xb)[t] = o;
    }
  } else {
    const int idx = (b - 512) * 256 + tid;
#pragma unroll
    for (int u = 0; u < 4; ++u) {
      const int t = u * 65536 + idx;
      const float4 v = ((const float4*)Wout)[t];
      ushort4 o;
      o.x = f2bf(v.x); o.y = f2bf(v.y); o.z = f2bf(v.z); o.w = f2bf(v.w);
      ((ushort4*)Woutb)[t] = o;
    }
  }
}

// ---------------------------------------------------------------------------
// Main GEMM, register-blocked: Y(512x2048) = xb @ Wcomb^T.
// 64 blocks x 256 thr; block tile 128x128; wave tile 64x64 (16 acc).
// MFMA:load = 2.0 (was 0.67); A/B traffic 64 MB (was 192 MB).
// ---------------------------------------------------------------------------
__global__ __launch_bounds__(256) void gemm_acv(
    const short* __restrict__ xb, const short* __restrict__ Wcomb,
    const float* __restrict__ ba32, const float* __restrict__ bc32,
    __half* __restrict__ a_buf, __half* __restrict__ cb_buf,
    __half* __restrict__ vT) {
  const int bb = blockIdx.x;           // 0..63
  const int tm = bb >> 4;              // 0..3
  const int tn = bb & 15;              // 0..15
  const int w = threadIdx.x >> 6;
  const int wm = w >> 1, wn = w & 1;
  const int lane = threadIdx.x & 63;
  const int m = lane & 15, quad = lane >> 4;

  const int row0 = tm * 128 + wm * 64;
  const int col0 = tn * 128 + wn * 64;

  const short* pa = xb + (size_t)(row0 + m) * DIM + quad * 8;
  const short* pb = Wcomb + (size_t)(col0 + m) * DIM + quad * 8;

  f32x4 acc[4][4];
#pragma unroll
  for (int mi = 0; mi < 4; ++mi)
#pragma unroll
    for (int ni = 0; ni < 4; ++ni) acc[mi][ni] = (f32x4){0.f, 0.f, 0.f, 0.f};

#pragma unroll 2
  for (int k = 0; k < DIM; k += 32) {
    bf16x8 af[4], bf[4];
#pragma unroll
    for (int i = 0; i < 4; ++i) {
      af[i] = *(const bf16x8*)(pa + (size_t)i * 16 * DIM + k);
      bf[i] = *(const bf16x8*)(pb + (size_t)i * 16 * DIM + k);
    }
#pragma unroll
    for (int mi = 0; mi < 4; ++mi)
#pragma unroll
      for (int ni = 0; ni < 4; ++ni)
        acc[mi][ni] = __builtin_amdgcn_mfma_f32_16x16x32_bf16(
            af[mi], bf[ni], acc[mi][ni], 0, 0, 0);
  }

#pragma unroll
  for (int mi = 0; mi < 4; ++mi) {
#pragma unroll
    for (int ni = 0; ni < 4; ++ni) {
      const int o = col0 + ni * 16 + m;
#pragma unroll
      for (int r = 0; r < 4; ++r) {
        const int n = row0 + mi * 16 + quad * 4 + r;
        const float val = acc[mi][ni][r];
        if (o < 512) {
          const int hh = o >> 5, q = o & 31;
          a_buf[((size_t)hh * N_SEQ + n) * P + q] = __float2half(val + ba32[q]);
        } else if (o < 1024) {
          const int oo = o - 512, hh = oo >> 5, q = oo & 31;
          cb_buf[((size_t)hh * N_SEQ + n) * P + q] = __float2half(val + bc32[q]);
        } else {
          const int ov = o - 1024, hh = ov >> 6, d = ov & 63;
          vT[((size_t)hh * DH + d) * N_SEQ + n] = __float2half(val);
        }
      }
    }
  }
}

// ---------------------------------------------------------------------------
// Fused attention, 512 threads / 8 waves (2 waves/SIMD).
// Score phase: waves split (row-group g = w&3, jt parity = w>>2) -> balanced.
// ---------------------------------------------------------------------------
__device__ inline float rowscore(const H8& a, const H8& c, f16x8 w2f,
                                 f32x4 b2q, float4 w3q) {
  const f16x8 z = (f16x8)(_Float16)0;
  const f16x8 u = __builtin_elementwise_max(a.v + c.v, z);
  f32x4 acc = b2q;                     // MFMA C-in carries +b2 for free
  acc = __builtin_amdgcn_mfma_f32_16x16x32_f16(w2f, u, acc, 0, 0, 0);
  return fmaxf(acc[0], 0.f) * w3q.x + fmaxf(acc[1], 0.f) * w3q.y
       + fmaxf(acc[2], 0.f) * w3q.z + fmaxf(acc[3], 0.f) * w3q.w;
}

__device__ inline float quadreduce4(float p0, float p1, float p2, float p3,
                                    int quad) {
  const float sx = (quad & 1) ? p0 : p1;
  const float sy = (quad & 1) ? p2 : p3;
  const float rx = __shfl_xor(sx, 16);
  const float ry = __shfl_xor(sy, 16);
  const float aa = ((quad & 1) ? p1 : p0) + rx;
  const float bb = ((quad & 1) ? p3 : p2) + ry;
  const float sz = (quad & 2) ? aa : bb;
  const float rz = __shfl_xor(sz, 32);
  return ((quad & 2) ? bb : aa) + rz;
}

__global__ __launch_bounds__(512) void attn_fused(
    const __half* __restrict__ a_g, const __half* __restrict__ cb_g,
    const float* __restrict__ W2, const float* __restrict__ b2,
    const float* __restrict__ W3,
    const __half* __restrict__ vT, short* __restrict__ attnb) {
  const int p = blockIdx.x;            // 0..15 (mirror pair)
  const int h = blockIdx.y;
  const int tid = threadIdx.x;
  const int w = tid >> 6;              // 0..7
  const int lane = tid & 63;
  const int m = lane & 15, quad = lane >> 4;

  __shared__ __align__(16) __half probS[32][PSTR];   // 33.3 KB
  __shared__ float invS[32];

  const int tlo = p, thi = 31 - p;
  const int nlo = p + 1, nhi = 32 - p;

  // ---- phase 1: scores -> probS (f16, raw) ----
  {
    const int g = w & 3;               // row-group within each i-tile
    const int par = w >> 2;            // jt parity
    f16x8 w2f;
    {
      const float4* wp = (const float4*)(W2 + m * P + quad * 8);
      const float4 w0 = wp[0], w1 = wp[1];
      H8 uu;
      uu.h2[0] = __floats2half2_rn(w0.x, w0.y);
      uu.h2[1] = __floats2half2_rn(w0.z, w0.w);
      uu.h2[2] = __floats2half2_rn(w1.x, w1.y);
      uu.h2[3] = __floats2half2_rn(w1.z, w1.w);
      w2f = uu.v;
    }
    const float4 b2f = *(const float4*)(b2 + quad * 4);
    const f32x4 b2q = {b2f.x, b2f.y, b2f.z, b2f.w};
    const float4 w3q = *(const float4*)(W3 + quad * 4);

    H8 alo[4], ahi[4];
#pragma unroll
    for (int r = 0; r < 4; ++r) {
      alo[r].v = *(const f16x8*)(a_g + ((size_t)h * N_SEQ + tlo * 16 + 4 * g + r) * P + quad * 8);
      ahi[r].v = *(const f16x8*)(a_g + ((size_t)h * N_SEQ + thi * 16 + 4 * g + r) * P + quad * 8);
    }

    for (int jt = par; jt < nhi; jt += 2) {
      H8 cb;
      cb.v = *(const f16x8*)(cb_g + ((size_t)h * N_SEQ + jt * 16 + m) * P + quad * 8);
      const float q0 = rowscore(ahi[0], cb, w2f, b2q, w3q);
      const float q1 = rowscore(ahi[1], cb, w2f, b2q, w3q);
      const float q2 = rowscore(ahi[2], cb, w2f, b2q, w3q);
      const float q3 = rowscore(ahi[3], cb, w2f, b2q, w3q);
      const float fh = quadreduce4(q0, q1, q2, q3, quad);
      probS[16 + 4 * g + quad][jt * 16 + m] = __float2half(fh);
      if (jt < nlo) {
        const float s0 = rowscore(alo[0], cb, w2f, b2q, w3q);
        const float s1 = rowscore(alo[1], cb, w2f, b2q, w3q);
        const float s2 = rowscore(alo[2], cb, w2f, b2q, w3q);
        const float s3 = rowscore(alo[3], cb, w2f, b2q, w3q);
        const float fl = quadreduce4(s0, s1, s2, s3, quad);
        probS[4 * g + quad][jt * 16 + m] = __float2half(fl);
      }
    }
  }
  __syncthreads();

  // ---- phase 2: per-row softmax (16 lanes/row); unnormalized exp ----
  {
    const int lr = tid >> 4;             // 0..31
    const int c  = tid & 15;             // 16 lanes per row
    const int gi = (lr < 16) ? (tlo * 16 + lr) : (thi * 16 + (lr - 16));
    float mx = -1e30f;
#pragma unroll
    for (int k = 0; k < 4; ++k) {
      const int c0 = k * 128 + c * 8;
      if (c0 > gi) break;
      H8 vv; vv.v = *(const f16x8*)&probS[lr][c0];
#pragma unroll
      for (int uu = 0; uu < 8; ++uu) {
        const float s = __half2float(vv.h2[uu >> 1].data[uu & 1]);
        if (c0 + uu <= gi) mx = fmaxf(mx, s);
      }
    }
#pragma unroll
    for (int msk = 1; msk < 16; msk <<= 1) mx = fmaxf(mx, __shfl_xor(mx, msk));
    float sum = 0.f;
#pragma unroll
    for (int k = 0; k < 4; ++k) {
      const int c0 = k * 128 + c * 8;
      H8 vv; vv.v = *(const f16x8*)&probS[lr][c0];
      H8 o;
#pragma unroll
      for (int uu = 0; uu < 4; ++uu) {
        float e0 = 0.f, e1 = 0.f;
        if (c0 + 2 * uu <= gi) {
          e0 = __expf(__half2float(vv.h2[uu].data[0]) - mx);
          if (c0 + 2 * uu + 1 <= gi)
            e1 = __expf(__half2float(vv.h2[uu].data[1]) - mx);
        }
        sum += e0 + e1;
        o.h2[uu] = __floats2half2_rn(e0, e1);
      }
      *(f16x8*)&probS[lr][c0] = o.v;
    }
#pragma unroll
    for (int msk = 1; msk < 16; msk <<= 1) sum += __shfl_xor(sum, msk);
    if (c == 0) invS[lr] = 1.f / sum;
  }
  __syncthreads();

  // ---- phase 3: PV. wave w -> (tile = w>>2, d-tile = w&3) ----
  {
    const int half = w >> 2;
    const int d0 = (w & 3) * 16;
    const __half* pb = vT + ((size_t)h * DH + d0 + m) * N_SEQ + quad * 8;
    const int lbase = half ? 16 : 0;
    const int tile = half ? thi : tlo;
    const int nk = half ? ((33 - p) >> 1) : ((p + 2) >> 1);
    f32x4 acc = {0.f, 0.f, 0.f, 0.f};
    for (int k = 0; k < nk; ++k) {
      const f16x8 aa = *(const f16x8*)&probS[lbase + m][k * 32 + quad * 8];
      const f16x8 bb = *(const f16x8*)(pb + k * 32);
      acc = __builtin_amdgcn_mfma_f32_16x16x32_f16(aa, bb, acc, 0, 0, 0);
    }
#pragma unroll
    for (int r = 0; r < 4; ++r) {
      const int lrow = quad * 4 + r;
      const float val = acc[r] * invS[lbase + lrow];
      attnb[(size_t)(tile * 16 + lrow) * DIM + h * DH + d0 + m] = (short)f2bf(val);
    }
  }
}

// ---------------------------------------------------------------------------
// Output GEMM, register-blocked: out(512x1024) = attnb @ Woutb^T.
// 32 blocks x 256 thr; block tile 128x128; wave tile 64x64.
// ---------------------------------------------------------------------------
__global__ __launch_bounds__(256) void gemm_out16(
    const short* __restrict__ A, const short* __restrict__ B,
    float* __restrict__ C) {
  const int bb = blockIdx.x;           // 0..31
  const int tm = bb >> 3;              // 0..3
  const int tn = bb & 7;               // 0..7
  const int w = threadIdx.x >> 6;
  const int wm = w >> 1, wn = w & 1;
  const int lane = threadIdx.x & 63;
  const int m = lane & 15, quad = lane >> 4;

  const int row0 = tm * 128 + wm * 64;
  const int col0 = tn * 128 + wn * 64;

  const short* pa = A + (size_t)(row0 + m) * DIM + quad * 8;
  const short* pb = B + (size_t)(col0 + m) * DIM + quad * 8;

  f32x4 acc[4][4];
#pragma unroll
  for (int mi = 0; mi < 4; ++mi)
#pragma unroll
    for (int ni = 0; ni < 4; ++ni) acc[mi][ni] = (f32x4){0.f, 0.f, 0.f, 0.f};

#pragma unroll 2
  for (int k = 0; k < DIM; k += 32) {
    bf16x8 af[4], bf[4];
#pragma unroll
    for (int i = 0; i < 4; ++i) {
      af[i] = *(const bf16x8*)(pa + (size_t)i * 16 * DIM + k);
      bf[i] = *(const bf16x8*)(pb + (size_t)i * 16 * DIM + k);
    }
#pragma unroll
    for (int mi = 0; mi < 4; ++mi)
#pragma unroll
      for (int ni = 0; ni < 4; ++ni)
        acc[mi][ni] = __builtin_amdgcn_mfma_f32_16x16x32_bf16(
            af[mi], bf[ni], acc[mi][ni], 0, 0, 0);
  }

#pragma unroll
  for (int mi = 0; mi < 4; ++mi)
#pragma unroll
    for (int ni = 0; ni < 4; ++ni) {
      const int o = col0 + ni * 16 + m;
#pragma unroll
      for (int r = 0; r < 4; ++r) {
        const int n = row0 + mi * 16 + quad * 4 + r;
        C[(size_t)n * DIM + o] = acc[mi][ni][r];
      }
    }
}

// ---------------------------------------------------------------------------
extern "C" void kernel_launch(void* const* d_in, const int* in_sizes, int n_in,
                              void* d_out, int out_size, void* d_ws, size_t ws_size,
                              hipStream_t stream) {
  const float* x    = (const float*)d_in[0];
  const float* Wqkv = (const float*)d_in[1];
  const float* Wout = (const float*)d_in[2];
  const float* Wq   = (const float*)d_in[3];
  const float* bq   = (const float*)d_in[4];
  const float* Wk   = (const float*)d_in[5];
  const float* bk   = (const float*)d_in[6];
  const float* W1   = (const float*)d_in[7];
  const float* b1   = (const float*)d_in[8];
  const float* W2   = (const float*)d_in[9];
  const float* b2   = (const float*)d_in[10];
  const float* W3   = (const float*)d_in[11];
  float* out = (float*)d_out;

  float*  ws     = (float*)d_ws;
  float*  ba32   = ws;                                   // 32
  float*  bc32   = ba32 + 32;                            // 32 (b1 pre-folded)
  __half* a_buf  = (__half*)(bc32 + 32);                 // 16*512*32
  __half* cb_buf = a_buf + (size_t)HEADS * N_SEQ * P;    // 16*512*32
  __half* vT     = cb_buf + (size_t)HEADS * N_SEQ * P;   // 16*64*512
  short*  Wcomb  = (short*)(vT + (size_t)HEADS * DH * N_SEQ); // 2048*1024
  short*  xb     = Wcomb + (size_t)2048 * DIM;           // 512*1024
  short*  Woutb  = xb + (size_t)N_SEQ * DIM;             // 1024*1024
  short*  attnb  = Woutb + (size_t)DIM * DIM;            // 512*1024

  // 1) prep: weight folding + bf16 casts
  prep<<<768, 256, 0, stream>>>(Wqkv, Wq, bq, Wk, bk, W1, b1, x, Wout,
                                Wcomb, xb, Woutb, ba32, bc32);

  // 2) main GEMM -> fp16 a / cb / vT (register-blocked 128x128)
  gemm_acv<<<64, 256, 0, stream>>>(xb, Wcomb, ba32, bc32, a_buf, cb_buf, vT);

  // 3) fused scores + softmax + PV (8 waves/block)
  dim3 g3(16, HEADS);
  attn_fused<<<g3, 512, 0, stream>>>(a_buf, cb_buf, W2, b2, W3, vT, attnb);

  // 4) output GEMM (register-blocked 128x128)
  gemm_out16<<<32, 256, 0, stream>>>(attnb, Woutb, out);
}

// Round 4
// 163.417 us; speedup vs baseline: 1.6603x; 1.2209x over previous
//
#include <hip/hip_runtime.h>
#include <hip/hip_bf16.h>
#include <hip/hip_fp16.h>
#include <math.h>

#define N_SEQ 512
#define DIM   1024
#define HEADS 16
#define DH    64
#define P     32
#define P2    16
#define PSTR  520   // prob LDS row stride in halfs (16B-aligned rows)

typedef short    bf16x8 __attribute__((ext_vector_type(8)));
typedef _Float16 f16x8  __attribute__((ext_vector_type(8)));
typedef float    f32x4  __attribute__((ext_vector_type(4)));

__device__ inline unsigned short f2bf(float f) {
  union { float f; unsigned u; } v; v.f = f;
  unsigned r = (v.u + 0x7fffu + ((v.u >> 16) & 1u)) >> 16;
  return (unsigned short)r;
}

union H8 { f16x8 v; __half2 h2[4]; unsigned u32[4]; };

// ---------------------------------------------------------------------------
// Fused prep: weight folding + all bf16 casts. 768 blocks.
// ---------------------------------------------------------------------------
__global__ __launch_bounds__(256) void prep(
    const float* __restrict__ Wqkv, const float* __restrict__ Wq,
    const float* __restrict__ bq, const float* __restrict__ Wk,
    const float* __restrict__ bk, const float* __restrict__ W1,
    const float* __restrict__ b1,
    const float* __restrict__ x, const float* __restrict__ Wout,
    short* __restrict__ Wcomb, short* __restrict__ xb,
    short* __restrict__ Woutb, float* __restrict__ ba32,
    float* __restrict__ bc32) {
  const int b = blockIdx.x, tid = threadIdx.x;
  if (b < 256) {
    __shared__ float W1s[32][33];
    __shared__ float Wqs[32][65];
    __shared__ float wsm[32][65];
    __shared__ __align__(16) float qs[64][132];
    const int part = b >> 7, rem = b & 127;
    const int h = rem >> 3, c0 = (rem & 7) * 128;
    const int grow = part * 16 + h;
    for (int idx = tid; idx < 1024; idx += 256)
      W1s[idx >> 5][idx & 31] = W1[(idx >> 5) * 64 + part * 32 + (idx & 31)];
    const float* Wsel = part ? Wk : Wq;
    for (int idx = tid; idx < 2048; idx += 256)
      Wqs[idx >> 6][idx & 63] = Wsel[idx];
    for (int idx = tid; idx < 2048; idx += 256) {
      const int d = idx >> 5, c4 = idx & 31;
      *(float4*)&qs[d][c4 * 4] =
          *(const float4*)(Wqkv + (size_t)(d * 48 + grow) * DIM + c0 + c4 * 4);
    }
    __syncthreads();
    for (int idx = tid; idx < 2048; idx += 256) {
      const int q = idx >> 6, d = idx & 63;
      float s = 0.f;
#pragma unroll
      for (int p = 0; p < 32; ++p) s += W1s[q][p] * Wqs[p][d];
      wsm[q][d] = s;
    }
    __syncthreads();
    for (int idx = tid; idx < 4096; idx += 256) {
      const int q = idx >> 7, c = idx & 127;
      float s = 0.f;
#pragma unroll
      for (int d = 0; d < 64; ++d) s += wsm[q][d] * qs[d][c];
      Wcomb[(size_t)(part * 512 + h * 32 + q) * DIM + c0 + c] = (short)f2bf(s);
    }
    if (rem == 0 && tid < 32) {
      const float* bsel = part ? bk : bq;
      float s = 0.f;
#pragma unroll
      for (int p = 0; p < 32; ++p) s += W1s[tid][p] * bsel[p];
      if (part) s += b1[tid];          // fold b1 into bc32
      (part ? bc32 : ba32)[tid] = s;
    }
  } else if (b < 384) {
#pragma unroll
    for (int rr = 0; rr < 8; ++rr) {
      const int ov = (b - 256) * 8 + rr;
      const int h = ov >> 6, d = ov & 63;
      const float4 v = *(const float4*)(Wqkv + (size_t)(d * 48 + 32 + h) * DIM + tid * 4);
      ushort4 o;
      o.x = f2bf(v.x); o.y = f2bf(v.y); o.z = f2bf(v.z); o.w = f2bf(v.w);
      *(ushort4*)(Wcomb + (size_t)(1024 + ov) * DIM + tid * 4) = o;
    }
  } else if (b < 512) {
    const int idx = (b - 384) * 256 + tid;
#pragma unroll
    for (int u = 0; u < 4; ++u) {
      const int t = u * 32768 + idx;
      const float4 v = ((const float4*)x)[t];
      ushort4 o;
      o.x = f2bf(v.x); o.y = f2bf(v.y); o.z = f2bf(v.z); o.w = f2bf(v.w);
      ((ushort4*)xb)[t] = o;
    }
  } else {
    const int idx = (b - 512) * 256 + tid;
#pragma unroll
    for (int u = 0; u < 4; ++u) {
      const int t = u * 65536 + idx;
      const float4 v = ((const float4*)Wout)[t];
      ushort4 o;
      o.x = f2bf(v.x); o.y = f2bf(v.y); o.z = f2bf(v.z); o.w = f2bf(v.w);
      ((ushort4*)Woutb)[t] = o;
    }
  }
}

// ---------------------------------------------------------------------------
// Main GEMM: Y(512x2048) = xb @ Wcomb^T.
// 256 blocks x 512 thr (8 waves, 2/SIMD, all CUs). Block 64x64, wave 16x32.
// 4-deep register prefetch (static indices) -> ~12 loads in flight/wave.
// ---------------------------------------------------------------------------
__global__ __launch_bounds__(512) void gemm_acv(
    const short* __restrict__ xb, const short* __restrict__ Wcomb,
    const float* __restrict__ ba32, const float* __restrict__ bc32,
    __half* __restrict__ a_buf, __half* __restrict__ cb_buf,
    __half* __restrict__ vT) {
  const int bb = blockIdx.x;           // 0..255
  const int tm = bb >> 5;              // 0..7   (M/64)
  const int tn = bb & 31;              // 0..31  (N/64)
  const int w = threadIdx.x >> 6;      // 0..7
  const int wm = w >> 1, wn = w & 1;
  const int lane = threadIdx.x & 63;
  const int m = lane & 15, quad = lane >> 4;

  const int row0 = tm * 64 + wm * 16;
  const int col0 = tn * 64 + wn * 32;

  const short* pa  = xb + (size_t)(row0 + m) * DIM + quad * 8;
  const short* pb0 = Wcomb + (size_t)(col0 + m) * DIM + quad * 8;
  const short* pb1 = pb0 + (size_t)16 * DIM;

  bf16x8 abuf[4], b0buf[4], b1buf[4];
#pragma unroll
  for (int j = 0; j < 4; ++j) {
    abuf[j]  = *(const bf16x8*)(pa  + j * 32);
    b0buf[j] = *(const bf16x8*)(pb0 + j * 32);
    b1buf[j] = *(const bf16x8*)(pb1 + j * 32);
  }

  f32x4 acc0 = {0.f, 0.f, 0.f, 0.f}, acc1 = {0.f, 0.f, 0.f, 0.f};

#pragma unroll
  for (int ko = 0; ko < 8; ++ko) {
#pragma unroll
    for (int j = 0; j < 4; ++j) {
      const int k = ko * 4 + j;
      const bf16x8 av  = abuf[j];
      const bf16x8 b0v = b0buf[j];
      const bf16x8 b1v = b1buf[j];
      if (k + 4 < 32) {                // refill slot j with step k+4
        abuf[j]  = *(const bf16x8*)(pa  + (k + 4) * 32);
        b0buf[j] = *(const bf16x8*)(pb0 + (k + 4) * 32);
        b1buf[j] = *(const bf16x8*)(pb1 + (k + 4) * 32);
      }
      acc0 = __builtin_amdgcn_mfma_f32_16x16x32_bf16(av, b0v, acc0, 0, 0, 0);
      acc1 = __builtin_amdgcn_mfma_f32_16x16x32_bf16(av, b1v, acc1, 0, 0, 0);
    }
  }

#pragma unroll
  for (int r = 0; r < 4; ++r) {
    const int n = row0 + quad * 4 + r;
#pragma unroll
    for (int half = 0; half < 2; ++half) {
      const int o = col0 + half * 16 + m;
      const float val = half ? acc1[r] : acc0[r];
      if (o < 512) {
        const int hh = o >> 5, q = o & 31;
        a_buf[((size_t)hh * N_SEQ + n) * P + q] = __float2half(val + ba32[q]);
      } else if (o < 1024) {
        const int oo = o - 512, hh = oo >> 5, q = oo & 31;
        cb_buf[((size_t)hh * N_SEQ + n) * P + q] = __float2half(val + bc32[q]);
      } else {
        const int ov = o - 1024, hh = ov >> 6, d = ov & 63;
        vT[((size_t)hh * DH + d) * N_SEQ + n] = __float2half(val);
      }
    }
  }
}

// ---------------------------------------------------------------------------
// Fused attention, 512 threads / 8 waves (2 waves/SIMD).
// ---------------------------------------------------------------------------
__device__ inline float rowscore(const H8& a, const H8& c, f16x8 w2f,
                                 f32x4 b2q, float4 w3q) {
  const f16x8 z = (f16x8)(_Float16)0;
  const f16x8 u = __builtin_elementwise_max(a.v + c.v, z);
  f32x4 acc = b2q;                     // MFMA C-in carries +b2 for free
  acc = __builtin_amdgcn_mfma_f32_16x16x32_f16(w2f, u, acc, 0, 0, 0);
  return fmaxf(acc[0], 0.f) * w3q.x + fmaxf(acc[1], 0.f) * w3q.y
       + fmaxf(acc[2], 0.f) * w3q.z + fmaxf(acc[3], 0.f) * w3q.w;
}

__device__ inline float quadreduce4(float p0, float p1, float p2, float p3,
                                    int quad) {
  const float sx = (quad & 1) ? p0 : p1;
  const float sy = (quad & 1) ? p2 : p3;
  const float rx = __shfl_xor(sx, 16);
  const float ry = __shfl_xor(sy, 16);
  const float aa = ((quad & 1) ? p1 : p0) + rx;
  const float bb = ((quad & 1) ? p3 : p2) + ry;
  const float sz = (quad & 2) ? aa : bb;
  const float rz = __shfl_xor(sz, 32);
  return ((quad & 2) ? bb : aa) + rz;
}

__global__ __launch_bounds__(512) void attn_fused(
    const __half* __restrict__ a_g, const __half* __restrict__ cb_g,
    const float* __restrict__ W2, const float* __restrict__ b2,
    const float* __restrict__ W3,
    const __half* __restrict__ vT, short* __restrict__ attnb) {
  const int p = blockIdx.x;            // 0..15 (mirror pair)
  const int h = blockIdx.y;
  const int tid = threadIdx.x;
  const int w = tid >> 6;              // 0..7
  const int lane = tid & 63;
  const int m = lane & 15, quad = lane >> 4;

  __shared__ __align__(16) __half probS[32][PSTR];   // 33.3 KB
  __shared__ float invS[32];

  const int tlo = p, thi = 31 - p;
  const int nlo = p + 1, nhi = 32 - p;

  // ---- phase 1: scores -> probS (f16, raw) ----
  {
    const int g = w & 3;               // row-group within each i-tile
    const int par = w >> 2;            // jt parity
    f16x8 w2f;
    {
      const float4* wp = (const float4*)(W2 + m * P + quad * 8);
      const float4 w0 = wp[0], w1 = wp[1];
      H8 uu;
      uu.h2[0] = __floats2half2_rn(w0.x, w0.y);
      uu.h2[1] = __floats2half2_rn(w0.z, w0.w);
      uu.h2[2] = __floats2half2_rn(w1.x, w1.y);
      uu.h2[3] = __floats2half2_rn(w1.z, w1.w);
      w2f = uu.v;
    }
    const float4 b2f = *(const float4*)(b2 + quad * 4);
    const f32x4 b2q = {b2f.x, b2f.y, b2f.z, b2f.w};
    const float4 w3q = *(const float4*)(W3 + quad * 4);

    H8 alo[4], ahi[4];
#pragma unroll
    for (int r = 0; r < 4; ++r) {
      alo[r].v = *(const f16x8*)(a_g + ((size_t)h * N_SEQ + tlo * 16 + 4 * g + r) * P + quad * 8);
      ahi[r].v = *(const f16x8*)(a_g + ((size_t)h * N_SEQ + thi * 16 + 4 * g + r) * P + quad * 8);
    }

    for (int jt = par; jt < nhi; jt += 2) {
      H8 cb;
      cb.v = *(const f16x8*)(cb_g + ((size_t)h * N_SEQ + jt * 16 + m) * P + quad * 8);
      const float q0 = rowscore(ahi[0], cb, w2f, b2q, w3q);
      const float q1 = rowscore(ahi[1], cb, w2f, b2q, w3q);
      const float q2 = rowscore(ahi[2], cb, w2f, b2q, w3q);
      const float q3 = rowscore(ahi[3], cb, w2f, b2q, w3q);
      const float fh = quadreduce4(q0, q1, q2, q3, quad);
      probS[16 + 4 * g + quad][jt * 16 + m] = __float2half(fh);
      if (jt < nlo) {
        const float s0 = rowscore(alo[0], cb, w2f, b2q, w3q);
        const float s1 = rowscore(alo[1], cb, w2f, b2q, w3q);
        const float s2 = rowscore(alo[2], cb, w2f, b2q, w3q);
        const float s3 = rowscore(alo[3], cb, w2f, b2q, w3q);
        const float fl = quadreduce4(s0, s1, s2, s3, quad);
        probS[4 * g + quad][jt * 16 + m] = __float2half(fl);
      }
    }
  }
  __syncthreads();

  // ---- phase 2: per-row softmax (16 lanes/row); unnormalized exp ----
  {
    const int lr = tid >> 4;             // 0..31
    const int c  = tid & 15;             // 16 lanes per row
    const int gi = (lr < 16) ? (tlo * 16 + lr) : (thi * 16 + (lr - 16));
    float mx = -1e30f;
#pragma unroll
    for (int k = 0; k < 4; ++k) {
      const int c0 = k * 128 + c * 8;
      if (c0 > gi) break;
      H8 vv; vv.v = *(const f16x8*)&probS[lr][c0];
#pragma unroll
      for (int uu = 0; uu < 8; ++uu) {
        const float s = __half2float(vv.h2[uu >> 1].data[uu & 1]);
        if (c0 + uu <= gi) mx = fmaxf(mx, s);
      }
    }
#pragma unroll
    for (int msk = 1; msk < 16; msk <<= 1) mx = fmaxf(mx, __shfl_xor(mx, msk));
    float sum = 0.f;
#pragma unroll
    for (int k = 0; k < 4; ++k) {
      const int c0 = k * 128 + c * 8;
      H8 vv; vv.v = *(const f16x8*)&probS[lr][c0];
      H8 o;
#pragma unroll
      for (int uu = 0; uu < 4; ++uu) {
        float e0 = 0.f, e1 = 0.f;
        if (c0 + 2 * uu <= gi) {
          e0 = __expf(__half2float(vv.h2[uu].data[0]) - mx);
          if (c0 + 2 * uu + 1 <= gi)
            e1 = __expf(__half2float(vv.h2[uu].data[1]) - mx);
        }
        sum += e0 + e1;
        o.h2[uu] = __floats2half2_rn(e0, e1);
      }
      *(f16x8*)&probS[lr][c0] = o.v;
    }
#pragma unroll
    for (int msk = 1; msk < 16; msk <<= 1) sum += __shfl_xor(sum, msk);
    if (c == 0) invS[lr] = 1.f / sum;
  }
  __syncthreads();

  // ---- phase 3: PV. wave w -> (tile = w>>2, d-tile = w&3) ----
  {
    const int half = w >> 2;
    const int d0 = (w & 3) * 16;
    const __half* pb = vT + ((size_t)h * DH + d0 + m) * N_SEQ + quad * 8;
    const int lbase = half ? 16 : 0;
    const int tile = half ? thi : tlo;
    const int nk = half ? ((33 - p) >> 1) : ((p + 2) >> 1);
    f32x4 acc = {0.f, 0.f, 0.f, 0.f};
    for (int k = 0; k < nk; ++k) {
      const f16x8 aa = *(const f16x8*)&probS[lbase + m][k * 32 + quad * 8];
      const f16x8 bb = *(const f16x8*)(pb + k * 32);
      acc = __builtin_amdgcn_mfma_f32_16x16x32_f16(aa, bb, acc, 0, 0, 0);
    }
#pragma unroll
    for (int r = 0; r < 4; ++r) {
      const int lrow = quad * 4 + r;
      const float val = acc[r] * invS[lbase + lrow];
      attnb[(size_t)(tile * 16 + lrow) * DIM + h * DH + d0 + m] = (short)f2bf(val);
    }
  }
}

// ---------------------------------------------------------------------------
// Output GEMM: out(512x1024) = attnb @ Woutb^T.
// 256 blocks x 512 thr. Block 32x64, wave 16x16, 4-deep register prefetch.
// ---------------------------------------------------------------------------
__global__ __launch_bounds__(512) void gemm_out16(
    const short* __restrict__ A, const short* __restrict__ B,
    float* __restrict__ C) {
  const int bb = blockIdx.x;           // 0..255
  const int tm = bb >> 4;              // 0..15 (M/32)
  const int tn = bb & 15;              // 0..15 (N/64)
  const int w = threadIdx.x >> 6;      // 0..7
  const int wm = w & 1, wn = w >> 1;
  const int lane = threadIdx.x & 63;
  const int m = lane & 15, quad = lane >> 4;

  const int row0 = tm * 32 + wm * 16;
  const int col0 = tn * 64 + wn * 16;

  const short* pa = A + (size_t)(row0 + m) * DIM + quad * 8;
  const short* pb = B + (size_t)(col0 + m) * DIM + quad * 8;

  bf16x8 abuf[4], bbuf[4];
#pragma unroll
  for (int j = 0; j < 4; ++j) {
    abuf[j] = *(const bf16x8*)(pa + j * 32);
    bbuf[j] = *(const bf16x8*)(pb + j * 32);
  }

  f32x4 acc = {0.f, 0.f, 0.f, 0.f};
#pragma unroll
  for (int ko = 0; ko < 8; ++ko) {
#pragma unroll
    for (int j = 0; j < 4; ++j) {
      const int k = ko * 4 + j;
      const bf16x8 av = abuf[j];
      const bf16x8 bv = bbuf[j];
      if (k + 4 < 32) {
        abuf[j] = *(const bf16x8*)(pa + (k + 4) * 32);
        bbuf[j] = *(const bf16x8*)(pb + (k + 4) * 32);
      }
      acc = __builtin_amdgcn_mfma_f32_16x16x32_bf16(av, bv, acc, 0, 0, 0);
    }
  }

#pragma unroll
  for (int r = 0; r < 4; ++r)
    C[(size_t)(row0 + quad * 4 + r) * DIM + col0 + m] = acc[r];
}

// ---------------------------------------------------------------------------
extern "C" void kernel_launch(void* const* d_in, const int* in_sizes, int n_in,
                              void* d_out, int out_size, void* d_ws, size_t ws_size,
                              hipStream_t stream) {
  const float* x    = (const float*)d_in[0];
  const float* Wqkv = (const float*)d_in[1];
  const float* Wout = (const float*)d_in[2];
  const float* Wq   = (const float*)d_in[3];
  const float* bq   = (const float*)d_in[4];
  const float* Wk   = (const float*)d_in[5];
  const float* bk   = (const float*)d_in[6];
  const float* W1   = (const float*)d_in[7];
  const float* b1   = (const float*)d_in[8];
  const float* W2   = (const float*)d_in[9];
  const float* b2   = (const float*)d_in[10];
  const float* W3   = (const float*)d_in[11];
  float* out = (float*)d_out;

  float*  ws     = (float*)d_ws;
  float*  ba32   = ws;                                   // 32
  float*  bc32   = ba32 + 32;                            // 32 (b1 pre-folded)
  __half* a_buf  = (__half*)(bc32 + 32);                 // 16*512*32
  __half* cb_buf = a_buf + (size_t)HEADS * N_SEQ * P;    // 16*512*32
  __half* vT     = cb_buf + (size_t)HEADS * N_SEQ * P;   // 16*64*512
  short*  Wcomb  = (short*)(vT + (size_t)HEADS * DH * N_SEQ); // 2048*1024
  short*  xb     = Wcomb + (size_t)2048 * DIM;           // 512*1024
  short*  Woutb  = xb + (size_t)N_SEQ * DIM;             // 1024*1024
  short*  attnb  = Woutb + (size_t)DIM * DIM;            // 512*1024

  // 1) prep: weight folding + bf16 casts
  prep<<<768, 256, 0, stream>>>(Wqkv, Wq, bq, Wk, bk, W1, b1, x, Wout,
                                Wcomb, xb, Woutb, ba32, bc32);

  // 2) main GEMM -> fp16 a / cb / vT (full machine, 4-deep prefetch)
  gemm_acv<<<256, 512, 0, stream>>>(xb, Wcomb, ba32, bc32, a_buf, cb_buf, vT);

  // 3) fused scores + softmax + PV (8 waves/block)
  dim3 g3(16, HEADS);
  attn_fused<<<g3, 512, 0, stream>>>(a_buf, cb_buf, W2, b2, W3, vT, attnb);

  // 4) output GEMM (full machine, 4-deep prefetch)
  gemm_out16<<<256, 512, 0, stream>>>(attnb, Woutb, out);
}

// Round 5
// 159.981 us; speedup vs baseline: 1.6959x; 1.0215x over previous
//
#include <hip/hip_runtime.h>
#include <hip/hip_bf16.h>
#include <hip/hip_fp16.h>
#include <math.h>

#define N_SEQ 512
#define DIM   1024
#define HEADS 16
#define DH    64
#define P     32
#define P2    16
#define PSTR  520   // prob LDS row stride in halfs (16B-aligned rows)

typedef short    bf16x8 __attribute__((ext_vector_type(8)));
typedef _Float16 f16x8  __attribute__((ext_vector_type(8)));
typedef float    f32x4  __attribute__((ext_vector_type(4)));

__device__ inline unsigned short f2bf(float f) {
  union { float f; unsigned u; } v; v.f = f;
  unsigned r = (v.u + 0x7fffu + ((v.u >> 16) & 1u)) >> 16;
  return (unsigned short)r;
}

union H8 { f16x8 v; __half2 h2[4]; unsigned u32[4]; };

// ---------------------------------------------------------------------------
// Fused prep: weight folding + all bf16 casts. 768 blocks.
// Fold phase B: qs stored transposed -> per-thread qsT row hoisted to VGPRs,
// wsm read as b128 broadcasts. FMA order over d unchanged (bit-identical).
// ---------------------------------------------------------------------------
__global__ __launch_bounds__(256) void prep(
    const float* __restrict__ Wqkv, const float* __restrict__ Wq,
    const float* __restrict__ bq, const float* __restrict__ Wk,
    const float* __restrict__ bk, const float* __restrict__ W1,
    const float* __restrict__ b1,
    const float* __restrict__ x, const float* __restrict__ Wout,
    short* __restrict__ Wcomb, short* __restrict__ xb,
    short* __restrict__ Woutb, float* __restrict__ ba32,
    float* __restrict__ bc32) {
  const int b = blockIdx.x, tid = threadIdx.x;
  if (b < 256) {
    __shared__ float W1s[32][33];
    __shared__ float Wqs[32][65];
    __shared__ float wsm[32][65];
    __shared__ __align__(16) float qsT[128][65];
    const int part = b >> 7, rem = b & 127;
    const int h = rem >> 3, c0 = (rem & 7) * 128;
    const int grow = part * 16 + h;
    for (int idx = tid; idx < 1024; idx += 256)
      W1s[idx >> 5][idx & 31] = W1[(idx >> 5) * 64 + part * 32 + (idx & 31)];
    const float* Wsel = part ? Wk : Wq;
    for (int idx = tid; idx < 2048; idx += 256)
      Wqs[idx >> 6][idx & 63] = Wsel[idx];
    for (int idx = tid; idx < 2048; idx += 256) {
      const int d = idx >> 5, c4 = idx & 31;
      const float4 v =
          *(const float4*)(Wqkv + (size_t)(d * 48 + grow) * DIM + c0 + c4 * 4);
      qsT[c4 * 4 + 0][d] = v.x;
      qsT[c4 * 4 + 1][d] = v.y;
      qsT[c4 * 4 + 2][d] = v.z;
      qsT[c4 * 4 + 3][d] = v.w;
    }
    __syncthreads();
    for (int idx = tid; idx < 2048; idx += 256) {
      const int q = idx >> 6, d = idx & 63;
      float s = 0.f;
#pragma unroll
      for (int p = 0; p < 32; ++p) s += W1s[q][p] * Wqs[p][d];
      wsm[q][d] = s;
    }
    __syncthreads();
    {
      const int c = tid & 127;
      float qr[64];
#pragma unroll
      for (int d4 = 0; d4 < 16; ++d4)
        *(float4*)&qr[d4 * 4] = *(const float4*)&qsT[c][d4 * 4];
#pragma unroll
      for (int step = 0; step < 16; ++step) {
        const int idx = step * 256 + tid;
        const int q = idx >> 7;
        float s = 0.f;
#pragma unroll
        for (int d = 0; d < 64; ++d) s += wsm[q][d] * qr[d];
        Wcomb[(size_t)(part * 512 + h * 32 + q) * DIM + c0 + c] = (short)f2bf(s);
      }
    }
    if (rem == 0 && tid < 32) {
      const float* bsel = part ? bk : bq;
      float s = 0.f;
#pragma unroll
      for (int p = 0; p < 32; ++p) s += W1s[tid][p] * bsel[p];
      if (part) s += b1[tid];          // fold b1 into bc32
      (part ? bc32 : ba32)[tid] = s;
    }
  } else if (b < 384) {
#pragma unroll
    for (int rr = 0; rr < 8; ++rr) {
      const int ov = (b - 256) * 8 + rr;
      const int h = ov >> 6, d = ov & 63;
      const float4 v = *(const float4*)(Wqkv + (size_t)(d * 48 + 32 + h) * DIM + tid * 4);
      ushort4 o;
      o.x = f2bf(v.x); o.y = f2bf(v.y); o.z = f2bf(v.z); o.w = f2bf(v.w);
      *(ushort4*)(Wcomb + (size_t)(1024 + ov) * DIM + tid * 4) = o;
    }
  } else if (b < 512) {
    const int idx = (b - 384) * 256 + tid;
#pragma unroll
    for (int u = 0; u < 4; ++u) {
      const int t = u * 32768 + idx;
      const float4 v = ((const float4*)x)[t];
      ushort4 o;
      o.x = f2bf(v.x); o.y = f2bf(v.y); o.z = f2bf(v.z); o.w = f2bf(v.w);
      ((ushort4*)xb)[t] = o;
    }
  } else {
    const int idx = (b - 512) * 256 + tid;
#pragma unroll
    for (int u = 0; u < 4; ++u) {
      const int t = u * 65536 + idx;
      const float4 v = ((const float4*)Wout)[t];
      ushort4 o;
      o.x = f2bf(v.x); o.y = f2bf(v.y); o.z = f2bf(v.z); o.w = f2bf(v.w);
      ((ushort4*)Woutb)[t] = o;
    }
  }
}

// ---------------------------------------------------------------------------
// Main GEMM: Y(512x2048) = xb @ Wcomb^T.
// 256 blocks x 512 thr (8 waves, 2/SIMD, all CUs). Block 64x64, wave 16x32.
// 4-deep register prefetch (static indices) -> ~12 loads in flight/wave.
// ---------------------------------------------------------------------------
__global__ __launch_bounds__(512) void gemm_acv(
    const short* __restrict__ xb, const short* __restrict__ Wcomb,
    const float* __restrict__ ba32, const float* __restrict__ bc32,
    __half* __restrict__ a_buf, __half* __restrict__ cb_buf,
    __half* __restrict__ vT) {
  const int bb = blockIdx.x;           // 0..255
  const int tm = bb >> 5;              // 0..7   (M/64)
  const int tn = bb & 31;              // 0..31  (N/64)
  const int w = threadIdx.x >> 6;      // 0..7
  const int wm = w >> 1, wn = w & 1;
  const int lane = threadIdx.x & 63;
  const int m = lane & 15, quad = lane >> 4;

  const int row0 = tm * 64 + wm * 16;
  const int col0 = tn * 64 + wn * 32;

  const short* pa  = xb + (size_t)(row0 + m) * DIM + quad * 8;
  const short* pb0 = Wcomb + (size_t)(col0 + m) * DIM + quad * 8;
  const short* pb1 = pb0 + (size_t)16 * DIM;

  bf16x8 abuf[4], b0buf[4], b1buf[4];
#pragma unroll
  for (int j = 0; j < 4; ++j) {
    abuf[j]  = *(const bf16x8*)(pa  + j * 32);
    b0buf[j] = *(const bf16x8*)(pb0 + j * 32);
    b1buf[j] = *(const bf16x8*)(pb1 + j * 32);
  }

  f32x4 acc0 = {0.f, 0.f, 0.f, 0.f}, acc1 = {0.f, 0.f, 0.f, 0.f};

#pragma unroll
  for (int ko = 0; ko < 8; ++ko) {
#pragma unroll
    for (int j = 0; j < 4; ++j) {
      const int k = ko * 4 + j;
      const bf16x8 av  = abuf[j];
      const bf16x8 b0v = b0buf[j];
      const bf16x8 b1v = b1buf[j];
      if (k + 4 < 32) {                // refill slot j with step k+4
        abuf[j]  = *(const bf16x8*)(pa  + (k + 4) * 32);
        b0buf[j] = *(const bf16x8*)(pb0 + (k + 4) * 32);
        b1buf[j] = *(const bf16x8*)(pb1 + (k + 4) * 32);
      }
      acc0 = __builtin_amdgcn_mfma_f32_16x16x32_bf16(av, b0v, acc0, 0, 0, 0);
      acc1 = __builtin_amdgcn_mfma_f32_16x16x32_bf16(av, b1v, acc1, 0, 0, 0);
    }
  }

#pragma unroll
  for (int r = 0; r < 4; ++r) {
    const int n = row0 + quad * 4 + r;
#pragma unroll
    for (int half = 0; half < 2; ++half) {
      const int o = col0 + half * 16 + m;
      const float val = half ? acc1[r] : acc0[r];
      if (o < 512) {
        const int hh = o >> 5, q = o & 31;
        a_buf[((size_t)hh * N_SEQ + n) * P + q] = __float2half(val + ba32[q]);
      } else if (o < 1024) {
        const int oo = o - 512, hh = oo >> 5, q = oo & 31;
        cb_buf[((size_t)hh * N_SEQ + n) * P + q] = __float2half(val + bc32[q]);
      } else {
        const int ov = o - 1024, hh = ov >> 6, d = ov & 63;
        vT[((size_t)hh * DH + d) * N_SEQ + n] = __float2half(val);
      }
    }
  }
}

// ---------------------------------------------------------------------------
// Fused attention: one block per (i-tile t, head h). 512 blocks x 256 thr
// (4 waves; 2 blocks/CU). blockIdx remap pairs t with 31-t per CU.
// 2-deep register prefetch on cb (scores) and vT (PV).
// ---------------------------------------------------------------------------
__device__ inline float rowscore(const H8& a, const H8& c, f16x8 w2f,
                                 f32x4 b2q, float4 w3q) {
  const f16x8 z = (f16x8)(_Float16)0;
  const f16x8 u = __builtin_elementwise_max(a.v + c.v, z);
  f32x4 acc = b2q;                     // MFMA C-in carries +b2 for free
  acc = __builtin_amdgcn_mfma_f32_16x16x32_f16(w2f, u, acc, 0, 0, 0);
  return fmaxf(acc[0], 0.f) * w3q.x + fmaxf(acc[1], 0.f) * w3q.y
       + fmaxf(acc[2], 0.f) * w3q.z + fmaxf(acc[3], 0.f) * w3q.w;
}

__device__ inline float quadreduce4(float p0, float p1, float p2, float p3,
                                    int quad) {
  const float sx = (quad & 1) ? p0 : p1;
  const float sy = (quad & 1) ? p2 : p3;
  const float rx = __shfl_xor(sx, 16);
  const float ry = __shfl_xor(sy, 16);
  const float aa = ((quad & 1) ? p1 : p0) + rx;
  const float bb = ((quad & 1) ? p3 : p2) + ry;
  const float sz = (quad & 2) ? aa : bb;
  const float rz = __shfl_xor(sz, 32);
  return ((quad & 2) ? bb : aa) + rz;
}

__global__ __launch_bounds__(256) void attn_fused(
    const __half* __restrict__ a_g, const __half* __restrict__ cb_g,
    const float* __restrict__ W2, const float* __restrict__ b2,
    const float* __restrict__ W3,
    const __half* __restrict__ vT, short* __restrict__ attnb) {
  // remap so co-resident blocks (c, c+256) get t and 31-t (balanced CU load)
  const int xx = blockIdx.x, yy = blockIdx.y;
  const int t = (yy & 8) ? (31 - xx) : xx;   // i-tile 0..31
  const int h = yy;                           // head 0..15
  const int tid = threadIdx.x;
  const int w = tid >> 6;              // 0..3
  const int lane = tid & 63;
  const int m = lane & 15, quad = lane >> 4;

  __shared__ __align__(16) __half probS[16][PSTR];   // 16.6 KB
  __shared__ float invS[16];

  const int nj = t + 1;                // j-tiles 0..t

  // ---- phase 1: scores -> probS (f16, raw). wave w -> rows 4w..4w+3 ----
  {
    f16x8 w2f;
    {
      const float4* wp = (const float4*)(W2 + m * P + quad * 8);
      const float4 w0 = wp[0], w1 = wp[1];
      H8 uu;
      uu.h2[0] = __floats2half2_rn(w0.x, w0.y);
      uu.h2[1] = __floats2half2_rn(w0.z, w0.w);
      uu.h2[2] = __floats2half2_rn(w1.x, w1.y);
      uu.h2[3] = __floats2half2_rn(w1.z, w1.w);
      w2f = uu.v;
    }
    const float4 b2f = *(const float4*)(b2 + quad * 4);
    const f32x4 b2q = {b2f.x, b2f.y, b2f.z, b2f.w};
    const float4 w3q = *(const float4*)(W3 + quad * 4);

    H8 ar[4];
#pragma unroll
    for (int r = 0; r < 4; ++r)
      ar[r].v = *(const f16x8*)(a_g + ((size_t)h * N_SEQ + t * 16 + 4 * w + r) * P + quad * 8);

    const __half* cbbase = cb_g + ((size_t)h * N_SEQ + m) * P + quad * 8;
    H8 cbn;
    cbn.v = *(const f16x8*)cbbase;     // jt = 0
    for (int jt = 0; jt < nj; ++jt) {
      const H8 cb = cbn;
      if (jt + 1 < nj)
        cbn.v = *(const f16x8*)(cbbase + (size_t)(jt + 1) * 16 * P);
      const float s0 = rowscore(ar[0], cb, w2f, b2q, w3q);
      const float s1 = rowscore(ar[1], cb, w2f, b2q, w3q);
      const float s2 = rowscore(ar[2], cb, w2f, b2q, w3q);
      const float s3 = rowscore(ar[3], cb, w2f, b2q, w3q);
      const float fl = quadreduce4(s0, s1, s2, s3, quad);
      probS[4 * w + quad][jt * 16 + m] = __float2half(fl);
    }
  }
  __syncthreads();

  // ---- phase 2: per-row softmax (16 rows x 16 lanes); unnormalized exp ----
  {
    const int lr = tid >> 4;             // 0..15
    const int c  = tid & 15;             // 16 lanes per row
    const int gi = t * 16 + lr;          // causal column bound
    float mx = -1e30f;
#pragma unroll
    for (int k = 0; k < 4; ++k) {
      const int c0 = k * 128 + c * 8;
      if (c0 > gi) break;
      H8 vv; vv.v = *(const f16x8*)&probS[lr][c0];
#pragma unroll
      for (int uu = 0; uu < 8; ++uu) {
        const float s = __half2float(vv.h2[uu >> 1].data[uu & 1]);
        if (c0 + uu <= gi) mx = fmaxf(mx, s);
      }
    }
#pragma unroll
    for (int msk = 1; msk < 16; msk <<= 1) mx = fmaxf(mx, __shfl_xor(mx, msk));
    float sum = 0.f;
#pragma unroll
    for (int k = 0; k < 4; ++k) {
      const int c0 = k * 128 + c * 8;
      H8 vv; vv.v = *(const f16x8*)&probS[lr][c0];
      H8 o;
#pragma unroll
      for (int uu = 0; uu < 4; ++uu) {
        float e0 = 0.f, e1 = 0.f;
        if (c0 + 2 * uu <= gi) {
          e0 = __expf(__half2float(vv.h2[uu].data[0]) - mx);
          if (c0 + 2 * uu + 1 <= gi)
            e1 = __expf(__half2float(vv.h2[uu].data[1]) - mx);
        }
        sum += e0 + e1;
        o.h2[uu] = __floats2half2_rn(e0, e1);
      }
      *(f16x8*)&probS[lr][c0] = o.v;     // zeros beyond causal bound
    }
#pragma unroll
    for (int msk = 1; msk < 16; msk <<= 1) sum += __shfl_xor(sum, msk);
    if (c == 0) invS[lr] = 1.f / sum;
  }
  __syncthreads();

  // ---- phase 3: PV. wave w -> d-tile w. vT 2-deep prefetch ----
  {
    const int d0 = w * 16;
    const __half* pb = vT + ((size_t)h * DH + d0 + m) * N_SEQ + quad * 8;
    const int nk = (t + 2) >> 1;       // ceil(nj*16 / 32)
    f32x4 acc = {0.f, 0.f, 0.f, 0.f};
    f16x8 vb = *(const f16x8*)pb;
    for (int k = 0; k < nk; ++k) {
      const f16x8 bb = vb;
      if (k + 1 < nk) vb = *(const f16x8*)(pb + (k + 1) * 32);
      const f16x8 aa = *(const f16x8*)&probS[m][k * 32 + quad * 8];
      acc = __builtin_amdgcn_mfma_f32_16x16x32_f16(aa, bb, acc, 0, 0, 0);
    }
#pragma unroll
    for (int r = 0; r < 4; ++r) {
      const int lrow = quad * 4 + r;
      const float val = acc[r] * invS[lrow];
      attnb[(size_t)(t * 16 + lrow) * DIM + h * DH + d0 + m] = (short)f2bf(val);
    }
  }
}

// ---------------------------------------------------------------------------
// Output GEMM: out(512x1024) = attnb @ Woutb^T.
// 256 blocks x 512 thr. Block 32x64, wave 16x16, 4-deep register prefetch.
// ---------------------------------------------------------------------------
__global__ __launch_bounds__(512) void gemm_out16(
    const short* __restrict__ A, const short* __restrict__ B,
    float* __restrict__ C) {
  const int bb = blockIdx.x;           // 0..255
  const int tm = bb >> 4;              // 0..15 (M/32)
  const int tn = bb & 15;              // 0..15 (N/64)
  const int w = threadIdx.x >> 6;      // 0..7
  const int wm = w & 1, wn = w >> 1;
  const int lane = threadIdx.x & 63;
  const int m = lane & 15, quad = lane >> 4;

  const int row0 = tm * 32 + wm * 16;
  const int col0 = tn * 64 + wn * 16;

  const short* pa = A + (size_t)(row0 + m) * DIM + quad * 8;
  const short* pb = B + (size_t)(col0 + m) * DIM + quad * 8;

  bf16x8 abuf[4], bbuf[4];
#pragma unroll
  for (int j = 0; j < 4; ++j) {
    abuf[j] = *(const bf16x8*)(pa + j * 32);
    bbuf[j] = *(const bf16x8*)(pb + j * 32);
  }

  f32x4 acc = {0.f, 0.f, 0.f, 0.f};
#pragma unroll
  for (int ko = 0; ko < 8; ++ko) {
#pragma unroll
    for (int j = 0; j < 4; ++j) {
      const int k = ko * 4 + j;
      const bf16x8 av = abuf[j];
      const bf16x8 bv = bbuf[j];
      if (k + 4 < 32) {
        abuf[j] = *(const bf16x8*)(pa + (k + 4) * 32);
        bbuf[j] = *(const bf16x8*)(pb + (k + 4) * 32);
      }
      acc = __builtin_amdgcn_mfma_f32_16x16x32_bf16(av, bv, acc, 0, 0, 0);
    }
  }

#pragma unroll
  for (int r = 0; r < 4; ++r)
    C[(size_t)(row0 + quad * 4 + r) * DIM + col0 + m] = acc[r];
}

// ---------------------------------------------------------------------------
extern "C" void kernel_launch(void* const* d_in, const int* in_sizes, int n_in,
                              void* d_out, int out_size, void* d_ws, size_t ws_size,
                              hipStream_t stream) {
  const float* x    = (const float*)d_in[0];
  const float* Wqkv = (const float*)d_in[1];
  const float* Wout = (const float*)d_in[2];
  const float* Wq   = (const float*)d_in[3];
  const float* bq   = (const float*)d_in[4];
  const float* Wk   = (const float*)d_in[5];
  const float* bk   = (const float*)d_in[6];
  const float* W1   = (const float*)d_in[7];
  const float* b1   = (const float*)d_in[8];
  const float* W2   = (const float*)d_in[9];
  const float* b2   = (const float*)d_in[10];
  const float* W3   = (const float*)d_in[11];
  float* out = (float*)d_out;

  float*  ws     = (float*)d_ws;
  float*  ba32   = ws;                                   // 32
  float*  bc32   = ba32 + 32;                            // 32 (b1 pre-folded)
  __half* a_buf  = (__half*)(bc32 + 32);                 // 16*512*32
  __half* cb_buf = a_buf + (size_t)HEADS * N_SEQ * P;    // 16*512*32
  __half* vT     = cb_buf + (size_t)HEADS * N_SEQ * P;   // 16*64*512
  short*  Wcomb  = (short*)(vT + (size_t)HEADS * DH * N_SEQ); // 2048*1024
  short*  xb     = Wcomb + (size_t)2048 * DIM;           // 512*1024
  short*  Woutb  = xb + (size_t)N_SEQ * DIM;             // 1024*1024
  short*  attnb  = Woutb + (size_t)DIM * DIM;            // 512*1024

  // 1) prep: weight folding + bf16 casts
  prep<<<768, 256, 0, stream>>>(Wqkv, Wq, bq, Wk, bk, W1, b1, x, Wout,
                                Wcomb, xb, Woutb, ba32, bc32);

  // 2) main GEMM -> fp16 a / cb / vT (full machine, 4-deep prefetch)
  gemm_acv<<<256, 512, 0, stream>>>(xb, Wcomb, ba32, bc32, a_buf, cb_buf, vT);

  // 3) fused scores + softmax + PV (512 blocks, balanced t-pairing, prefetch)
  dim3 g3(32, HEADS);
  attn_fused<<<g3, 256, 0, stream>>>(a_buf, cb_buf, W2, b2, W3, vT, attnb);

  // 4) output GEMM (full machine, 4-deep prefetch)
  gemm_out16<<<256, 512, 0, stream>>>(attnb, Woutb, out);
}